// Round 2
// baseline (605.516 us; speedup 1.0000x reference)
//
#include <hip/hip_runtime.h>
#include <hip/hip_bf16.h>

typedef __bf16 bf16x4 __attribute__((ext_vector_type(4)));
typedef __bf16 bf16x8 __attribute__((ext_vector_type(8)));
typedef float  floatx4 __attribute__((ext_vector_type(4)));

// ---------------------------------------------------------------------------
// Kernel 1: Cayley transform + bf16 MFMA-fragment packing.
//   Q = (I + S)(I - S)^{-1} = 2*(I - S)^{-1} - I,  S = 0.5*(M - M^T)
// Gauss-Jordan in rank-1 form: publish UNSCALED pivot row+column, then
//   row_i -= (col_i/piv) * row_k  (i != k);  row_k *= 1/piv.
// Double-buffered publish arrays -> ONE barrier per k (was 3).
// Blocks 0..63: R -> w1pack; 64..127: L -> w2pack.
// Packed layout per matrix (4096 bf16):
//   dst[(kh*4+grp)*512 + lane*8 + j] = Q[16*grp + (lane&15)][32*kh + 8*(lane>>4) + j]
// = the mfma_f32_16x16x32_bf16 B-fragment load order.
// ---------------------------------------------------------------------------
__global__ __launch_bounds__(256) void cayley_pack_kernel(
    const float* __restrict__ L, const float* __restrict__ R,
    __bf16* __restrict__ ws) {
  __shared__ float Ms[64][65];
  __shared__ float Pa[2][64];
  __shared__ float Pi[2][64];
  __shared__ float fcol[2][64];

  const int blk = blockIdx.x;
  const int t = threadIdx.x;
  const float* M = (blk < 64) ? (R + (size_t)blk * 4096)
                              : (L + (size_t)(blk - 64) * 4096);
  __bf16* dst = ws + (size_t)blk * 4096;

  for (int u = 0; u < 16; ++u) {
    int idx = u * 256 + t;
    Ms[idx >> 6][idx & 63] = M[idx];
  }
  __syncthreads();

  const int i = t >> 2;        // row 0..63 (4 threads per row)
  const int g = t & 3;         // column group
  const int jb = g * 16;
  float a[16], v[16];
#pragma unroll
  for (int jj = 0; jj < 16; ++jj) {
    int j = jb + jj;
    float s = 0.5f * (Ms[i][j] - Ms[j][i]);
    a[jj] = (i == j ? 1.0f : 0.0f) - s;   // A = I - S
    v[jj] = (i == j ? 1.0f : 0.0f);       // Inv = I
  }
  __syncthreads();

#pragma unroll 4
  for (int k = 0; k < 64; ++k) {
    const int kb = k & 1;
    // publish unscaled column k and unscaled row k (double-buffered)
    if (g == (k >> 4)) fcol[kb][i] = a[k & 15];
    if (i == k) {
#pragma unroll
      for (int jj = 0; jj < 16; ++jj) { Pa[kb][jb + jj] = a[jj]; Pi[kb][jb + jj] = v[jj]; }
    }
    __syncthreads();
    const float ip = 1.0f / Pa[kb][k];    // pivot = a[k][k] (unscaled)
    if (i == k) {
#pragma unroll
      for (int jj = 0; jj < 16; ++jj) { a[jj] *= ip; v[jj] *= ip; }
    } else {
      const float f = fcol[kb][i] * ip;
#pragma unroll
      for (int jj = 0; jj < 16; ++jj) {
        a[jj] -= f * Pa[kb][jb + jj];
        v[jj] -= f * Pi[kb][jb + jj];
      }
    }
    // no second barrier: iter k+1 publishes into buffer (k+1)&1, and the
    // per-iter barrier orders iter-(k+2) overwrites behind all iter-k reads.
  }

  // Q = 2*Ainv - I staged to LDS for the packing shuffle
#pragma unroll
  for (int jj = 0; jj < 16; ++jj) {
    int j = jb + jj;
    Ms[i][j] = 2.0f * v[jj] - (i == j ? 1.0f : 0.0f);
  }
  __syncthreads();

  const int lane = t & 63;
  const int grp = t >> 6;
  const int colq = lane & 15;
  const int quad = lane >> 4;
#pragma unroll
  for (int kh = 0; kh < 2; ++kh) {
    bf16x8 pk;
#pragma unroll
    for (int j8 = 0; j8 < 8; ++j8)
      pk[j8] = (__bf16)Ms[16 * grp + colq][32 * kh + 8 * quad + j8];
    *(bf16x8*)(dst + (kh * 4 + grp) * 512 + lane * 8) = pk;
  }
}

// ---------------------------------------------------------------------------
// Kernel 2: fused butterfly, FULL 16-row A-fragments (was 8 rows duplicated).
// 512 threads = 8 waves, 16 batch rows per block, inter = 128 KB dynamic LDS
// -> 1 block/CU. Halves weight traffic, MFMA count, x-load and store
// instructions PER OUTPUT vs the 8-row version (rounds 0-1 proved occupancy
// is not the binder; per-output latency exposure is).
// Stage 1: wave wv owns r in [8wv,8wv+8): out1[b,r,q] -> inter[l=q][b][r]
// (bf16, XOR chunk swizzle cs = wv ^ (b&7) ^ (l&7)). One barrier.
// Stage 2: wave (wv&3) owns 16 l's, (wv>>2) picks the s-half; in-register
// l-transpose keeps global stores 64B-contiguous per lane.
// MFMA layouts (gfx950 16x16x32_bf16): A[m=lane&15][k=(lane>>4)*8+j],
// B[k=(lane>>4)*8+j][n=lane&15], C col=lane&15 row=(lane>>4)*4+reg.
// ---------------------------------------------------------------------------
__global__ __launch_bounds__(512, 2) void butterfly_kernel(
    const float* __restrict__ x, const __bf16* __restrict__ ws,
    float* __restrict__ out) {
  extern __shared__ short interS[];        // 131072 B = 128 KB -> 1 block/CU
  __bf16* inter = (__bf16*)interS;

  const int t = threadIdx.x;
  const int wv = t >> 6;                   // wave 0..7
  const int lane = t & 63;
  const int col = lane & 15;
  const int quad = lane >> 4;
  const size_t b0 = (size_t)blockIdx.x * 16;

  const __bf16* w1 = ws;                   // cayley(R), stage-1 weights
  const __bf16* w2 = ws + 64 * 4096;       // cayley(L), stage-2 weights

  // ---------------- stage 1: wave wv owns r in [8*wv, 8*wv+8) -------------
  const float* xrow = x + (b0 + (size_t)col) * 4096;   // 16 distinct rows
#pragma unroll
  for (int rg = 0; rg < 2; ++rg) {
    const int r0 = wv * 8 + rg * 4;
    bf16x8 afrag[4][2];
#pragma unroll
    for (int ir = 0; ir < 4; ++ir) {
      const float* src = xrow + (r0 + ir) * 64 + quad * 8;
#pragma unroll
      for (int kh = 0; kh < 2; ++kh) {
        floatx4 u = *(const floatx4*)(src + kh * 32);
        floatx4 w = *(const floatx4*)(src + kh * 32 + 4);
        bf16x8 f;
        f[0] = (__bf16)u[0]; f[1] = (__bf16)u[1];
        f[2] = (__bf16)u[2]; f[3] = (__bf16)u[3];
        f[4] = (__bf16)w[0]; f[5] = (__bf16)w[1];
        f[6] = (__bf16)w[2]; f[7] = (__bf16)w[3];
        afrag[ir][kh] = f;
      }
    }
#pragma unroll
    for (int qc = 0; qc < 4; ++qc) {
      floatx4 vals[4];
#pragma unroll
      for (int ir = 0; ir < 4; ++ir) {
        const int r = r0 + ir;
        bf16x8 bf0 = *(const bf16x8*)(w1 + (size_t)r * 4096 + (0 * 4 + qc) * 512 + lane * 8);
        bf16x8 bf1 = *(const bf16x8*)(w1 + (size_t)r * 4096 + (1 * 4 + qc) * 512 + lane * 8);
        floatx4 acc = {0.f, 0.f, 0.f, 0.f};
        acc = __builtin_amdgcn_mfma_f32_16x16x32_bf16(afrag[ir][0], bf0, acc, 0, 0, 0);
        acc = __builtin_amdgcn_mfma_f32_16x16x32_bf16(afrag[ir][1], bf1, acc, 0, 0, 0);
        vals[ir] = acc;
      }
      const int l = qc * 16 + col;          // l = q
#pragma unroll
      for (int reg = 0; reg < 4; ++reg) {
        const int b = quad * 4 + reg;       // batch row 0..15 (all valid now)
        bf16x4 pk;
        pk[0] = (__bf16)vals[0][reg];
        pk[1] = (__bf16)vals[1][reg];
        pk[2] = (__bf16)vals[2][reg];
        pk[3] = (__bf16)vals[3][reg];
        const int cs = wv ^ (b & 7) ^ (l & 7);   // bank swizzle on r-chunk
        *(bf16x4*)(inter + l * 1024 + b * 64 + cs * 8 + rg * 4) = pk;
      }
    }
  }
  __syncthreads();

  // ---------------- stage 2: wave (wv&3) owns l in [16*(wv&3), +16);
  // wv>>2 picks which half of the s range this wave computes. -------------
  const int wl = wv & 3;
  const int b = col;                        // A-frag row = batch row 0..15
  float* outb = out + b0 * 4096;
#pragma unroll
  for (int sci = 0; sci < 2; ++sci) {
    const int sc = (wv >> 2) * 2 + sci;     // 0..3 across wave pairs
    floatx4 vals[16];
#pragma unroll
    for (int l16 = 0; l16 < 16; ++l16) {
      const int l = wl * 16 + l16;
      const int swz = (b & 7) ^ (l & 7);
      bf16x8 a0 = *(const bf16x8*)(inter + l * 1024 + b * 64 + (quad ^ swz) * 8);
      bf16x8 a1 = *(const bf16x8*)(inter + l * 1024 + b * 64 + ((4 + quad) ^ swz) * 8);
      bf16x8 bf0 = *(const bf16x8*)(w2 + (size_t)l * 4096 + (0 * 4 + sc) * 512 + lane * 8);
      bf16x8 bf1 = *(const bf16x8*)(w2 + (size_t)l * 4096 + (1 * 4 + sc) * 512 + lane * 8);
      floatx4 acc = {0.f, 0.f, 0.f, 0.f};
      acc = __builtin_amdgcn_mfma_f32_16x16x32_bf16(a0, bf0, acc, 0, 0, 0);
      acc = __builtin_amdgcn_mfma_f32_16x16x32_bf16(a1, bf1, acc, 0, 0, 0);
      vals[l16] = acc;
    }
    const int s = sc * 16 + col;
#pragma unroll
    for (int reg = 0; reg < 4; ++reg) {
      const int bb = quad * 4 + reg;        // batch row 0..15 (all valid now)
      float* dstp = outb + (size_t)bb * 4096 + s * 64 + wl * 16;
#pragma unroll
      for (int q4 = 0; q4 < 4; ++q4) {      // 64B contiguous per (bb,s)
        floatx4 vv;
        vv[0] = vals[q4 * 4 + 0][reg];
        vv[1] = vals[q4 * 4 + 1][reg];
        vv[2] = vals[q4 * 4 + 2][reg];
        vv[3] = vals[q4 * 4 + 3][reg];
        *(floatx4*)(dstp + q4 * 4) = vv;
      }
    }
  }
}

extern "C" void kernel_launch(void* const* d_in, const int* in_sizes, int n_in,
                              void* d_out, int out_size, void* d_ws, size_t ws_size,
                              hipStream_t stream) {
  const float* x = (const float*)d_in[0];
  const float* L = (const float*)d_in[1];
  const float* R = (const float*)d_in[2];
  float* out = (float*)d_out;
  __bf16* ws = (__bf16*)d_ws;               // needs 128*4096*2 = 1 MB

  const int nrows = in_sizes[0] / 4096;     // 16384

  cayley_pack_kernel<<<128, 256, 0, stream>>>(L, R, ws);
  butterfly_kernel<<<nrows / 16, 512, 131072, stream>>>(x, ws, out);
}

// Round 3
// 522.236 us; speedup vs baseline: 1.1595x; 1.1595x over previous
//
#include <hip/hip_runtime.h>
#include <hip/hip_bf16.h>

typedef __bf16 bf16x4 __attribute__((ext_vector_type(4)));
typedef __bf16 bf16x8 __attribute__((ext_vector_type(8)));
typedef float  floatx4 __attribute__((ext_vector_type(4)));

// ---------------------------------------------------------------------------
// Kernel 1: Cayley transform + bf16 MFMA-fragment packing.
//   Q = (I + S)(I - S)^{-1} = 2*(I - S)^{-1} - I,  S = 0.5*(M - M^T)
// Gauss-Jordan rank-1 form, double-buffered publishes -> 1 barrier per k.
// Blocks 0..63: R -> w1pack; 64..127: L -> w2pack.
// Packed layout per matrix (4096 bf16):
//   dst[(kh*4+grp)*512 + lane*8 + j] = Q[16*grp + (lane&15)][32*kh + 8*(lane>>4) + j]
// = the mfma_f32_16x16x32_bf16 B-fragment load order.
// ---------------------------------------------------------------------------
__global__ __launch_bounds__(256) void cayley_pack_kernel(
    const float* __restrict__ L, const float* __restrict__ R,
    __bf16* __restrict__ ws) {
  __shared__ float Ms[64][65];
  __shared__ float Pa[2][64];
  __shared__ float Pi[2][64];
  __shared__ float fcol[2][64];

  const int blk = blockIdx.x;
  const int t = threadIdx.x;
  const float* M = (blk < 64) ? (R + (size_t)blk * 4096)
                              : (L + (size_t)(blk - 64) * 4096);
  __bf16* dst = ws + (size_t)blk * 4096;

  for (int u = 0; u < 16; ++u) {
    int idx = u * 256 + t;
    Ms[idx >> 6][idx & 63] = M[idx];
  }
  __syncthreads();

  const int i = t >> 2;        // row 0..63 (4 threads per row)
  const int g = t & 3;         // column group
  const int jb = g * 16;
  float a[16], v[16];
#pragma unroll
  for (int jj = 0; jj < 16; ++jj) {
    int j = jb + jj;
    float s = 0.5f * (Ms[i][j] - Ms[j][i]);
    a[jj] = (i == j ? 1.0f : 0.0f) - s;   // A = I - S
    v[jj] = (i == j ? 1.0f : 0.0f);       // Inv = I
  }
  __syncthreads();

  for (int k = 0; k < 64; ++k) {
    const int kb = k & 1;
    if (g == (k >> 4)) fcol[kb][i] = a[k & 15];
    if (i == k) {
#pragma unroll
      for (int jj = 0; jj < 16; ++jj) { Pa[kb][jb + jj] = a[jj]; Pi[kb][jb + jj] = v[jj]; }
    }
    __syncthreads();
    const float ip = 1.0f / Pa[kb][k];    // pivot = a[k][k] (unscaled)
    if (i == k) {
#pragma unroll
      for (int jj = 0; jj < 16; ++jj) { a[jj] *= ip; v[jj] *= ip; }
    } else {
      const float f = fcol[kb][i] * ip;
#pragma unroll
      for (int jj = 0; jj < 16; ++jj) {
        a[jj] -= f * Pa[kb][jb + jj];
        v[jj] -= f * Pi[kb][jb + jj];
      }
    }
    // barrier at top of next iter orders buffer reuse (double-buffered)
  }

#pragma unroll
  for (int jj = 0; jj < 16; ++jj) {
    int j = jb + jj;
    Ms[i][j] = 2.0f * v[jj] - (i == j ? 1.0f : 0.0f);
  }
  __syncthreads();

  const int lane = t & 63;
  const int grp = t >> 6;
  const int colq = lane & 15;
  const int quad = lane >> 4;
#pragma unroll
  for (int kh = 0; kh < 2; ++kh) {
    bf16x8 pk;
#pragma unroll
    for (int j8 = 0; j8 < 8; ++j8)
      pk[j8] = (__bf16)Ms[16 * grp + colq][32 * kh + 8 * quad + j8];
    *(bf16x8*)(dst + (kh * 4 + grp) * 512 + lane * 8) = pk;
  }
}

// ---------------------------------------------------------------------------
// Kernel 2: fused butterfly, 512 thr = 8 waves, 16 batch rows, 128 KB LDS.
// Round-2 post-mortem: time was pinned by per-wave VMEM serialization (each
// load issue->wait->consume, VGPR 84) + store scatter (64 lines / inst, 16B
// partial-line writes -> WRITE_SIZE 1.5x ideal). Fixes here:
//  (a) source-level load pipelining: x loads + first weight set issued
//      before conversion; weight sets prefetched one iteration ahead in both
//      stages; stage-2 A-fragments hoisted once (halves ds_reads).
//  (b) output bounced through LDS (reusing the dead inter buffer) in two
//      2048-col chunks -> global stores are contiguous 16 B/lane full lines.
// LDS swizzles: inter keeps the verified round-2 chunk XOR; bounce uses
// gp = g ^ ((g>>4)&7) on 16 B granules (bank-uniform write & read, bijective
// within each 128 B block).
// MFMA layouts (gfx950 16x16x32_bf16): A[m=lane&15][k=(lane>>4)*8+j],
// B[k=(lane>>4)*8+j][n=lane&15], C col=lane&15 row=(lane>>4)*4+reg.
// ---------------------------------------------------------------------------
__global__ __launch_bounds__(512, 2) void butterfly_kernel(
    const float* __restrict__ x, const __bf16* __restrict__ ws,
    float* __restrict__ out) {
  extern __shared__ short interS[];        // 131072 B
  __bf16* inter = (__bf16*)interS;
  float* bounce = (float*)interS;

  const int t = threadIdx.x;
  const int wv = t >> 6;                   // wave 0..7
  const int lane = t & 63;
  const int col = lane & 15;
  const int quad = lane >> 4;
  const size_t b0 = (size_t)blockIdx.x * 16;

  const __bf16* w1 = ws;                   // cayley(R), stage-1 weights
  const __bf16* w2 = ws + 64 * 4096;       // cayley(L), stage-2 weights

  // ---------------- stage 1: wave wv owns r in [8*wv, 8*wv+8) -------------
  const float* xrow = x + (b0 + (size_t)col) * 4096;   // 16 distinct rows
#pragma unroll
  for (int rg = 0; rg < 2; ++rg) {
    const int r0 = wv * 8 + rg * 4;
    // (1) issue all 16 x loads
    floatx4 xu[4][2], xw[4][2];
#pragma unroll
    for (int ir = 0; ir < 4; ++ir) {
      const float* src = xrow + (r0 + ir) * 64 + quad * 8;
#pragma unroll
      for (int kh = 0; kh < 2; ++kh) {
        xu[ir][kh] = *(const floatx4*)(src + kh * 32);
        xw[ir][kh] = *(const floatx4*)(src + kh * 32 + 4);
      }
    }
    // (2) issue first weight set (qc=0) before converting x — overlaps latency
    bf16x8 wfr[2][4][2];
#pragma unroll
    for (int ir = 0; ir < 4; ++ir)
#pragma unroll
      for (int kh = 0; kh < 2; ++kh)
        wfr[0][ir][kh] = *(const bf16x8*)(
            w1 + (size_t)(r0 + ir) * 4096 + (kh * 4 + 0) * 512 + lane * 8);
    // (3) convert x to A-fragments
    bf16x8 af[4][2];
#pragma unroll
    for (int ir = 0; ir < 4; ++ir)
#pragma unroll
      for (int kh = 0; kh < 2; ++kh) {
        bf16x8 f;
        f[0] = (__bf16)xu[ir][kh][0]; f[1] = (__bf16)xu[ir][kh][1];
        f[2] = (__bf16)xu[ir][kh][2]; f[3] = (__bf16)xu[ir][kh][3];
        f[4] = (__bf16)xw[ir][kh][0]; f[5] = (__bf16)xw[ir][kh][1];
        f[6] = (__bf16)xw[ir][kh][2]; f[7] = (__bf16)xw[ir][kh][3];
        af[ir][kh] = f;
      }
    // (4) qc loop with one-iteration weight prefetch
#pragma unroll
    for (int qc = 0; qc < 4; ++qc) {
      if (qc < 3) {
#pragma unroll
        for (int ir = 0; ir < 4; ++ir)
#pragma unroll
          for (int kh = 0; kh < 2; ++kh)
            wfr[(qc + 1) & 1][ir][kh] = *(const bf16x8*)(
                w1 + (size_t)(r0 + ir) * 4096 + (kh * 4 + qc + 1) * 512 + lane * 8);
      }
      floatx4 vals[4];
#pragma unroll
      for (int ir = 0; ir < 4; ++ir) {
        floatx4 acc = {0.f, 0.f, 0.f, 0.f};
        acc = __builtin_amdgcn_mfma_f32_16x16x32_bf16(af[ir][0], wfr[qc & 1][ir][0], acc, 0, 0, 0);
        acc = __builtin_amdgcn_mfma_f32_16x16x32_bf16(af[ir][1], wfr[qc & 1][ir][1], acc, 0, 0, 0);
        vals[ir] = acc;
      }
      const int l = qc * 16 + col;          // l = q
#pragma unroll
      for (int reg = 0; reg < 4; ++reg) {
        const int b = quad * 4 + reg;       // batch row 0..15
        bf16x4 pk;
        pk[0] = (__bf16)vals[0][reg];
        pk[1] = (__bf16)vals[1][reg];
        pk[2] = (__bf16)vals[2][reg];
        pk[3] = (__bf16)vals[3][reg];
        const int cs = wv ^ (b & 7) ^ (l & 7);   // r-chunk XOR swizzle
        *(bf16x4*)(inter + l * 1024 + b * 64 + cs * 8 + rg * 4) = pk;
      }
    }
  }
  __syncthreads();

  // ---------------- stage 2: wave wv owns l in [8*wv, 8*wv+8) -------------
  // Hoist A-fragments for all 8 l's once (they do not depend on s).
  bf16x8 A0[8], A1[8];
#pragma unroll
  for (int l16 = 0; l16 < 8; ++l16) {
    const int l = wv * 8 + l16;
    const int swz = (col & 7) ^ (l & 7);
    A0[l16] = *(const bf16x8*)(inter + l * 1024 + col * 64 + (quad ^ swz) * 8);
    A1[l16] = *(const bf16x8*)(inter + l * 1024 + col * 64 + ((4 + quad) ^ swz) * 8);
  }
  __syncthreads();                          // inter is now dead everywhere

  float* outb = out + b0 * 4096;
#pragma unroll
  for (int p = 0; p < 2; ++p) {             // output column chunk: s in [p*32, p*32+32)
    // preload w2 for l16=0
    bf16x8 wf2[2][2][2];                    // [l16&1][scloc][kh]
#pragma unroll
    for (int scloc = 0; scloc < 2; ++scloc)
#pragma unroll
      for (int kh = 0; kh < 2; ++kh)
        wf2[0][scloc][kh] = *(const bf16x8*)(
            w2 + (size_t)(wv * 8) * 4096 + (kh * 4 + p * 2 + scloc) * 512 + lane * 8);
    floatx4 acc[8][2];
#pragma unroll
    for (int l16 = 0; l16 < 8; ++l16) {
      if (l16 < 7) {
        const int ln = wv * 8 + l16 + 1;
#pragma unroll
        for (int scloc = 0; scloc < 2; ++scloc)
#pragma unroll
          for (int kh = 0; kh < 2; ++kh)
            wf2[(l16 + 1) & 1][scloc][kh] = *(const bf16x8*)(
                w2 + (size_t)ln * 4096 + (kh * 4 + p * 2 + scloc) * 512 + lane * 8);
      }
#pragma unroll
      for (int scloc = 0; scloc < 2; ++scloc) {
        floatx4 a = {0.f, 0.f, 0.f, 0.f};
        a = __builtin_amdgcn_mfma_f32_16x16x32_bf16(A0[l16], wf2[l16 & 1][scloc][0], a, 0, 0, 0);
        a = __builtin_amdgcn_mfma_f32_16x16x32_bf16(A1[l16], wf2[l16 & 1][scloc][1], a, 0, 0, 0);
        acc[l16][scloc] = a;
      }
    }
    // ---- bounce: acc -> LDS (f32, swizzled), chunk = [16 rows][2048 cols]
    // logical float (b, cc): cc = scloc*1024 + col*64 + wv*8 + h*4 + j
    // granule g = b*512 + cc/4; physical gp = g ^ ((g>>4)&7)
#pragma unroll
    for (int scloc = 0; scloc < 2; ++scloc)
#pragma unroll
      for (int reg = 0; reg < 4; ++reg)
#pragma unroll
        for (int h = 0; h < 2; ++h) {
          const int b = quad * 4 + reg;
          const int g = b * 512 + scloc * 256 + col * 16 + wv * 2 + h;
          const int gp = g ^ ((g >> 4) & 7);
          floatx4 pk;
          pk[0] = acc[h * 4 + 0][scloc][reg];
          pk[1] = acc[h * 4 + 1][scloc][reg];
          pk[2] = acc[h * 4 + 2][scloc][reg];
          pk[3] = acc[h * 4 + 3][scloc][reg];
          *(floatx4*)(bounce + gp * 4) = pk;
        }
    __syncthreads();
    // ---- contiguous full-line stores: wave wv stores rows 2wv, 2wv+1
#pragma unroll
    for (int rr = 0; rr < 2; ++rr) {
      const int b = wv * 2 + rr;
#pragma unroll
      for (int i = 0; i < 8; ++i) {
        const int g = b * 512 + i * 64 + lane;
        const int gp = g ^ ((g >> 4) & 7);
        floatx4 v = *(const floatx4*)(bounce + gp * 4);
        *(floatx4*)(outb + (size_t)b * 4096 + p * 2048 + i * 256 + lane * 4) = v;
      }
    }
    __syncthreads();   // store-side LDS reads done before next chunk's writes
  }
}

extern "C" void kernel_launch(void* const* d_in, const int* in_sizes, int n_in,
                              void* d_out, int out_size, void* d_ws, size_t ws_size,
                              hipStream_t stream) {
  const float* x = (const float*)d_in[0];
  const float* L = (const float*)d_in[1];
  const float* R = (const float*)d_in[2];
  float* out = (float*)d_out;
  __bf16* ws = (__bf16*)d_ws;               // needs 128*4096*2 = 1 MB

  const int nrows = in_sizes[0] / 4096;     // 16384

  cayley_pack_kernel<<<128, 256, 0, stream>>>(L, R, ws);
  butterfly_kernel<<<nrows / 16, 512, 131072, stream>>>(x, ws, out);
}

// Round 4
// 505.186 us; speedup vs baseline: 1.1986x; 1.0338x over previous
//
#include <hip/hip_runtime.h>
#include <hip/hip_bf16.h>

typedef __bf16 bf16x4 __attribute__((ext_vector_type(4)));
typedef __bf16 bf16x8 __attribute__((ext_vector_type(8)));
typedef float  floatx4 __attribute__((ext_vector_type(4)));

// ---------------------------------------------------------------------------
// Kernel 1: Cayley transform + bf16 MFMA-fragment packing.
//   Q = (I + S)(I - S)^{-1} = 2*(I - S)^{-1} - I,  S = 0.5*(M - M^T)
// Gauss-Jordan rank-1 form, double-buffered publishes -> 1 barrier per k.
// unroll 2 keeps kb = k&1 compile-time (rolled loop doubled cayley time, r3).
// Blocks 0..63: R -> w1pack; 64..127: L -> w2pack.
// Packed layout per matrix (4096 bf16):
//   dst[(kh*4+grp)*512 + lane*8 + j] = Q[16*grp + (lane&15)][32*kh + 8*(lane>>4) + j]
// = the mfma_f32_16x16x32_bf16 B-fragment load order.
// ---------------------------------------------------------------------------
__global__ __launch_bounds__(256) void cayley_pack_kernel(
    const float* __restrict__ L, const float* __restrict__ R,
    __bf16* __restrict__ ws) {
  __shared__ float Ms[64][65];
  __shared__ float Pa[2][64];
  __shared__ float Pi[2][64];
  __shared__ float fcol[2][64];

  const int blk = blockIdx.x;
  const int t = threadIdx.x;
  const float* M = (blk < 64) ? (R + (size_t)blk * 4096)
                              : (L + (size_t)(blk - 64) * 4096);
  __bf16* dst = ws + (size_t)blk * 4096;

  for (int u = 0; u < 16; ++u) {
    int idx = u * 256 + t;
    Ms[idx >> 6][idx & 63] = M[idx];
  }
  __syncthreads();

  const int i = t >> 2;        // row 0..63 (4 threads per row)
  const int g = t & 3;         // column group
  const int jb = g * 16;
  float a[16], v[16];
#pragma unroll
  for (int jj = 0; jj < 16; ++jj) {
    int j = jb + jj;
    float s = 0.5f * (Ms[i][j] - Ms[j][i]);
    a[jj] = (i == j ? 1.0f : 0.0f) - s;   // A = I - S
    v[jj] = (i == j ? 1.0f : 0.0f);       // Inv = I
  }
  __syncthreads();

#pragma unroll 2
  for (int k = 0; k < 64; ++k) {
    const int kb = k & 1;
    if (g == (k >> 4)) fcol[kb][i] = a[k & 15];
    if (i == k) {
#pragma unroll
      for (int jj = 0; jj < 16; ++jj) { Pa[kb][jb + jj] = a[jj]; Pi[kb][jb + jj] = v[jj]; }
    }
    __syncthreads();
    const float ip = 1.0f / Pa[kb][k];    // pivot = a[k][k] (unscaled)
    if (i == k) {
#pragma unroll
      for (int jj = 0; jj < 16; ++jj) { a[jj] *= ip; v[jj] *= ip; }
    } else {
      const float f = fcol[kb][i] * ip;
#pragma unroll
      for (int jj = 0; jj < 16; ++jj) {
        a[jj] -= f * Pa[kb][jb + jj];
        v[jj] -= f * Pi[kb][jb + jj];
      }
    }
    // barrier at top of next iter orders buffer reuse (double-buffered)
  }

#pragma unroll
  for (int jj = 0; jj < 16; ++jj) {
    int j = jb + jj;
    Ms[i][j] = 2.0f * v[jj] - (i == j ? 1.0f : 0.0f);
  }
  __syncthreads();

  const int lane = t & 63;
  const int grp = t >> 6;
  const int colq = lane & 15;
  const int quad = lane >> 4;
#pragma unroll
  for (int kh = 0; kh < 2; ++kh) {
    bf16x8 pk;
#pragma unroll
    for (int j8 = 0; j8 < 8; ++j8)
      pk[j8] = (__bf16)Ms[16 * grp + colq][32 * kh + 8 * quad + j8];
    *(bf16x8*)(dst + (kh * 4 + grp) * 512 + lane * 8) = pk;
  }
}

// ---------------------------------------------------------------------------
// Kernel 2: fused butterfly, 512 thr = 8 waves, 16 batch rows, 128 KB LDS.
// Round-3 got 259->~165us from prefetch-1 + LDS store bounce. Remaining gap
// to the 85us BW floor is load CONCURRENCY: sustaining 6.3 TB/s needs
// ~16-30 outstanding 16B loads per wave; prefetch-1 gives ~8-12. This round:
//  - stage 1: x loads for r-group 1 issued under r-group 0's MFMA loop
//    (16 HBM loads hidden under ~4 qc iterations); weight prefetch 2-deep
//    across 4 rotating buffers.
//  - stage 2: accumulate all 4 s-chunks at once (acc[8][4]) so each w2
//    fragment group loads ONCE (halves w2 issue count); A-frags + w2 group
//    prefetched 1 l16 ahead (8 loads / group in flight).
// Verified layouts unchanged from round 3 (passed): inter chunk XOR swizzle,
// bounce gp = g ^ ((g>>4)&7) on 16B granules, contiguous full-line stores.
// MFMA layouts (gfx950 16x16x32_bf16): A[m=lane&15][k=(lane>>4)*8+j],
// B[k=(lane>>4)*8+j][n=lane&15], C col=lane&15 row=(lane>>4)*4+reg.
// ---------------------------------------------------------------------------
__global__ __launch_bounds__(512, 2) void butterfly_kernel(
    const float* __restrict__ x, const __bf16* __restrict__ ws,
    float* __restrict__ out) {
  extern __shared__ short interS[];        // 131072 B
  __bf16* inter = (__bf16*)interS;
  float* bounce = (float*)interS;

  const int t = threadIdx.x;
  const int wv = t >> 6;                   // wave 0..7
  const int lane = t & 63;
  const int col = lane & 15;
  const int quad = lane >> 4;
  const size_t b0 = (size_t)blockIdx.x * 16;

  const __bf16* w1 = ws;                   // cayley(R), stage-1 weights
  const __bf16* w2 = ws + 64 * 4096;       // cayley(L), stage-2 weights

  const float* xrow = x + (b0 + (size_t)col) * 4096;   // 16 distinct rows

  // ---- stage-1 helpers (all-inline, static indices only) -----------------
  auto loadX = [&](int r0loc, floatx4 (&xu)[4][2], floatx4 (&xw)[4][2]) {
#pragma unroll
    for (int ir = 0; ir < 4; ++ir) {
      const float* src = xrow + (r0loc + ir) * 64 + quad * 8;
#pragma unroll
      for (int kh = 0; kh < 2; ++kh) {
        xu[ir][kh] = *(const floatx4*)(src + kh * 32);
        xw[ir][kh] = *(const floatx4*)(src + kh * 32 + 4);
      }
    }
  };
  auto cvtX = [&](floatx4 (&xu)[4][2], floatx4 (&xw)[4][2], bf16x8 (&af)[4][2]) {
#pragma unroll
    for (int ir = 0; ir < 4; ++ir)
#pragma unroll
      for (int kh = 0; kh < 2; ++kh) {
        bf16x8 f;
        f[0] = (__bf16)xu[ir][kh][0]; f[1] = (__bf16)xu[ir][kh][1];
        f[2] = (__bf16)xu[ir][kh][2]; f[3] = (__bf16)xu[ir][kh][3];
        f[4] = (__bf16)xw[ir][kh][0]; f[5] = (__bf16)xw[ir][kh][1];
        f[6] = (__bf16)xw[ir][kh][2]; f[7] = (__bf16)xw[ir][kh][3];
        af[ir][kh] = f;
      }
  };
  auto loadW1 = [&](int r0loc, int qc, bf16x8 (&wf)[4][2]) {
#pragma unroll
    for (int ir = 0; ir < 4; ++ir)
#pragma unroll
      for (int kh = 0; kh < 2; ++kh)
        wf[ir][kh] = *(const bf16x8*)(
            w1 + (size_t)(r0loc + ir) * 4096 + (kh * 4 + qc) * 512 + lane * 8);
  };
  auto doQC = [&](int rg, int qc, bf16x8 (&af)[4][2], bf16x8 (&wf)[4][2]) {
    floatx4 vals[4];
#pragma unroll
    for (int ir = 0; ir < 4; ++ir) {
      floatx4 acc = {0.f, 0.f, 0.f, 0.f};
      acc = __builtin_amdgcn_mfma_f32_16x16x32_bf16(af[ir][0], wf[ir][0], acc, 0, 0, 0);
      acc = __builtin_amdgcn_mfma_f32_16x16x32_bf16(af[ir][1], wf[ir][1], acc, 0, 0, 0);
      vals[ir] = acc;
    }
    const int l = qc * 16 + col;            // l = q
#pragma unroll
    for (int reg = 0; reg < 4; ++reg) {
      const int b = quad * 4 + reg;         // batch row 0..15
      bf16x4 pk;
      pk[0] = (__bf16)vals[0][reg];
      pk[1] = (__bf16)vals[1][reg];
      pk[2] = (__bf16)vals[2][reg];
      pk[3] = (__bf16)vals[3][reg];
      const int cs = wv ^ (b & 7) ^ (l & 7);   // r-chunk XOR swizzle
      *(bf16x4*)(inter + l * 1024 + b * 64 + cs * 8 + rg * 4) = pk;
    }
  };

  // ---- stage 1: wave wv owns r in [8*wv, 8*wv+8), pipelined across rg ----
  {
    const int rA = wv * 8;                  // r-group 0 (ir 0..3)
    const int rB = wv * 8 + 4;              // r-group 1
    floatx4 xu0[4][2], xw0[4][2];
    loadX(rA, xu0, xw0);                    // 16 HBM loads in flight
    bf16x8 wf[4][4][2];                     // 4 rotating weight buffers
    loadW1(rA, 0, wf[0]);
    loadW1(rA, 1, wf[1]);                   // +16 L2 loads in flight
    bf16x8 af0[4][2];
    cvtX(xu0, xw0, af0);
    floatx4 xu1[4][2], xw1[4][2];
    loadX(rB, xu1, xw1);                    // rg1 x loads hide under rg0 MFMAs
    loadW1(rA, 2, wf[2]);
    doQC(0, 0, af0, wf[0]);
    loadW1(rA, 3, wf[3]);
    doQC(0, 1, af0, wf[1]);
    loadW1(rB, 0, wf[0]);
    doQC(0, 2, af0, wf[2]);
    loadW1(rB, 1, wf[1]);
    doQC(0, 3, af0, wf[3]);
    bf16x8 af1[4][2];
    cvtX(xu1, xw1, af1);
    loadW1(rB, 2, wf[2]);
    doQC(1, 0, af1, wf[0]);
    loadW1(rB, 3, wf[3]);
    doQC(1, 1, af1, wf[1]);
    doQC(1, 2, af1, wf[2]);
    doQC(1, 3, af1, wf[3]);
  }
  __syncthreads();

  // ---- stage 2: wave wv owns l in [8*wv, 8*wv+8); all 4 s-chunks at once -
  auto loadA = [&](int l, bf16x8& a0, bf16x8& a1) {
    const int swz = (col & 7) ^ (l & 7);
    a0 = *(const bf16x8*)(inter + l * 1024 + col * 64 + (quad ^ swz) * 8);
    a1 = *(const bf16x8*)(inter + l * 1024 + col * 64 + ((4 + quad) ^ swz) * 8);
  };
  auto loadW2 = [&](int l, bf16x8 (&wf)[4][2]) {
#pragma unroll
    for (int sc = 0; sc < 4; ++sc)
#pragma unroll
      for (int kh = 0; kh < 2; ++kh)
        wf[sc][kh] = *(const bf16x8*)(
            w2 + (size_t)l * 4096 + (kh * 4 + sc) * 512 + lane * 8);
  };

  floatx4 acc[8][4];                        // [l16][sc]
  {
    bf16x8 A0[2], A1[2];
    bf16x8 w2f[2][4][2];
    loadA(wv * 8, A0[0], A1[0]);
    loadW2(wv * 8, w2f[0]);
#pragma unroll
    for (int l16 = 0; l16 < 8; ++l16) {
      if (l16 < 7) {                        // prefetch next l16 group
        loadA(wv * 8 + l16 + 1, A0[(l16 + 1) & 1], A1[(l16 + 1) & 1]);
        loadW2(wv * 8 + l16 + 1, w2f[(l16 + 1) & 1]);
      }
#pragma unroll
      for (int sc = 0; sc < 4; ++sc) {
        floatx4 a = {0.f, 0.f, 0.f, 0.f};
        a = __builtin_amdgcn_mfma_f32_16x16x32_bf16(A0[l16 & 1], w2f[l16 & 1][sc][0], a, 0, 0, 0);
        a = __builtin_amdgcn_mfma_f32_16x16x32_bf16(A1[l16 & 1], w2f[l16 & 1][sc][1], a, 0, 0, 0);
        acc[l16][sc] = a;
      }
    }
  }
  __syncthreads();                          // all inter reads done; inter dead

  float* outb = out + b0 * 4096;
#pragma unroll
  for (int p = 0; p < 2; ++p) {             // output column chunk [p*2048, +2048)
    // ---- bounce: acc -> LDS (f32, swizzled), chunk = [16 rows][2048 cols]
    // logical float (b, cc): cc = scloc*1024 + col*64 + wv*8 + h*4 + i
    // granule g = b*512 + cc/4; physical gp = g ^ ((g>>4)&7)
#pragma unroll
    for (int scloc = 0; scloc < 2; ++scloc)
#pragma unroll
      for (int reg = 0; reg < 4; ++reg)
#pragma unroll
        for (int h = 0; h < 2; ++h) {
          const int b = quad * 4 + reg;
          const int g = b * 512 + scloc * 256 + col * 16 + wv * 2 + h;
          const int gp = g ^ ((g >> 4) & 7);
          floatx4 pk;
          pk[0] = acc[h * 4 + 0][p * 2 + scloc][reg];
          pk[1] = acc[h * 4 + 1][p * 2 + scloc][reg];
          pk[2] = acc[h * 4 + 2][p * 2 + scloc][reg];
          pk[3] = acc[h * 4 + 3][p * 2 + scloc][reg];
          *(floatx4*)(bounce + gp * 4) = pk;
        }
    __syncthreads();
    // ---- contiguous full-line stores: wave wv stores rows 2wv, 2wv+1
#pragma unroll
    for (int rr = 0; rr < 2; ++rr) {
      const int b = wv * 2 + rr;
#pragma unroll
      for (int i = 0; i < 8; ++i) {
        const int g = b * 512 + i * 64 + lane;
        const int gp = g ^ ((g >> 4) & 7);
        floatx4 v = *(const floatx4*)(bounce + gp * 4);
        *(floatx4*)(outb + (size_t)b * 4096 + p * 2048 + i * 256 + lane * 4) = v;
      }
    }
    __syncthreads();   // store-side LDS reads done before next chunk's writes
  }
}

extern "C" void kernel_launch(void* const* d_in, const int* in_sizes, int n_in,
                              void* d_out, int out_size, void* d_ws, size_t ws_size,
                              hipStream_t stream) {
  const float* x = (const float*)d_in[0];
  const float* L = (const float*)d_in[1];
  const float* R = (const float*)d_in[2];
  float* out = (float*)d_out;
  __bf16* ws = (__bf16*)d_ws;               // needs 128*4096*2 = 1 MB

  const int nrows = in_sizes[0] / 4096;     // 16384

  cayley_pack_kernel<<<128, 256, 0, stream>>>(L, R, ws);
  butterfly_kernel<<<nrows / 16, 512, 131072, stream>>>(x, ws, out);
}